// Round 20
// baseline (3872.303 us; speedup 1.0000x reference)
//
#include <hip/hip_runtime.h>

#define H 1024
#define ITR 2048
#define NE 8
#define BT 32

typedef __attribute__((ext_vector_type(8))) short short8;
typedef __attribute__((ext_vector_type(4))) float f32x4;

__device__ __forceinline__ float bf2f(unsigned short u){
  union { unsigned int i; float f; } v; v.i = ((unsigned int)u) << 16; return v.f;
}
__device__ __forceinline__ unsigned short f2bf(float f){
  union { unsigned int i; float f; } v; v.f = f;
  unsigned int r = v.i + 0x7FFFu + ((v.i >> 16) & 1u);
  return (unsigned short)(r >> 16);
}
__device__ __forceinline__ void gload16(const void* g, void* l){
  __builtin_amdgcn_global_load_lds((const __attribute__((address_space(1))) void*)g,
                                   (__attribute__((address_space(3))) void*)l, 16, 0, 0);
}

// ---- dtype probe ----
__global__ __launch_bounds__(64) void detect_k(const unsigned int* __restrict__ xw,
                                               int* __restrict__ flag, int* __restrict__ cnt16){
  int lane = threadIdx.x;
  int c = 0;
  #pragma unroll
  for (int i = 0; i < 4; i++){
    unsigned u = xw[lane * 4 + i];
    int e = (u >> 7) & 0xFF;
    c += (e >= 100 && e <= 140) ? 1 : 0;
  }
  #pragma unroll
  for (int off = 32; off; off >>= 1) c += __shfl_xor(c, off);
  if (lane == 0) flag[0] = (c < 128) ? 1 : 0;
  if (lane < 16) cnt16[lane] = 0;
}

__device__ __forceinline__ void loadv16(const void* base, size_t off, int isf, float* out){
  if (isf){
    const float* p = (const float*)base + off;
    float4 a = *(const float4*)p, b = *(const float4*)(p + 4);
    float4 c = *(const float4*)(p + 8), d = *(const float4*)(p + 12);
    out[0]=a.x; out[1]=a.y; out[2]=a.z; out[3]=a.w;
    out[4]=b.x; out[5]=b.y; out[6]=b.z; out[7]=b.w;
    out[8]=c.x; out[9]=c.y; out[10]=c.z; out[11]=c.w;
    out[12]=d.x; out[13]=d.y; out[14]=d.z; out[15]=d.w;
  } else {
    const unsigned short* p = (const unsigned short*)base + off;
    uint4 a = *(const uint4*)p, b = *(const uint4*)(p + 8);
    unsigned short u[16];
    *(uint4*)u = a; *(uint4*)(u + 8) = b;
    #pragma unroll
    for (int j = 0; j < 16; j++) out[j] = bf2f(u[j]);
  }
}

// ---- transpose weights; mt 0/1 write INTERLEAVED WguT rows, mt 2 -> WdT ----
// WguT row for channel ch of matrix mt: (ch>>5)*64 + mt*32 + (ch&31)
__global__ __launch_bounds__(256) void trans_k(
    const void* __restrict__ rg, const void* __restrict__ ru, const void* __restrict__ rd,
    const void* __restrict__ sg, const void* __restrict__ su, const void* __restrict__ sd,
    unsigned short* __restrict__ arena, const int* __restrict__ flag)
{
  int slot = blockIdx.z / 3, mt = blockIdx.z % 3;
  int e = slot;                            // slot 8 => shared
  int R = (mt == 2) ? ITR : H;
  int C = (mt == 2) ? H : ITR;
  int c0 = blockIdx.x * 64, r0 = blockIdx.y * 64;
  if (c0 >= C || r0 >= R) return;
  const void* srcv;
  size_t eoff = 0;
  if (e == NE) srcv = (mt == 0) ? sg : ((mt == 1) ? su : sd);
  else { srcv = (mt == 0) ? rg : ((mt == 1) ? ru : rd); eoff = (size_t)e * H * ITR; }
  unsigned short* dst = arena + (size_t)slot * (3u * H * ITR)
                      + (mt == 2 ? (size_t)2 * H * ITR : 0);
  int isf = *flag;
  __shared__ unsigned short tile[64][72];
  int t = threadIdx.x;
  int row = t >> 3, c8 = (t & 7) * 8;
  #pragma unroll
  for (int p = 0; p < 2; p++){
    int r = r0 + row + p * 32;
    unsigned short v[8];
    if (isf){
      const float* s = (const float*)srcv + eoff + (size_t)r * C + c0 + c8;
      float4 a = *(const float4*)s, b = *(const float4*)(s + 4);
      v[0]=f2bf(a.x); v[1]=f2bf(a.y); v[2]=f2bf(a.z); v[3]=f2bf(a.w);
      v[4]=f2bf(b.x); v[5]=f2bf(b.y); v[6]=f2bf(b.z); v[7]=f2bf(b.w);
    } else {
      const unsigned short* s = (const unsigned short*)srcv + eoff + (size_t)r * C + c0 + c8;
      *(uint4*)v = *(const uint4*)s;
    }
    *(uint4*)&tile[row + p * 32][c8] = *(const uint4*)v;
  }
  __syncthreads();
  #pragma unroll
  for (int p = 0; p < 2; p++){
    int c = row + p * 32;
    int dc = c0 + c;
    int dr = (mt == 2) ? dc : (((dc >> 5) << 6) + mt * 32 + (dc & 31));
    unsigned short tmp[8];
    #pragma unroll
    for (int j = 0; j < 8; j++) tmp[j] = tile[c8 + j][c];
    *(uint4*)(dst + (size_t)dr * R + r0 + c8) = *(const uint4*)tmp;
  }
}

// ---- router: two lists (primary ctr 0..7 / secondary 8..15) ----
__global__ __launch_bounds__(256) void router2_k(
    const void* __restrict__ x, const void* __restrict__ lns, const void* __restrict__ lnb,
    const void* __restrict__ gw, int T, const int* __restrict__ flag,
    int* __restrict__ cnt16, int* __restrict__ lidx, float* __restrict__ lw)
{
  int isf = *flag;
  int tid = threadIdx.x, wv = tid >> 6, lane = tid & 63;
  int t0 = blockIdx.x * BT;
  __shared__ int scc[16], sbase[16];
  __shared__ int sei[2][BT], soi[2][BT];
  __shared__ float swv[2][BT];
  if (tid < 16) scc[tid] = 0;
  float sc[16], bi[16];
  loadv16(lns, (size_t)lane * 16, isf, sc);
  loadv16(lnb, (size_t)lane * 16, isf, bi);
  __syncthreads();

  for (int i = 0; i < BT / 4; i++){
    int tl = i * 4 + wv;
    int tok = t0 + tl;
    if (tok >= T) break;
    float v[16];
    loadv16(x, (size_t)tok * H + lane * 16, isf, v);
    float sum = 0.f, ss = 0.f;
    #pragma unroll
    for (int j = 0; j < 16; j++){ sum += v[j]; ss += v[j] * v[j]; }
    #pragma unroll
    for (int off = 32; off; off >>= 1){ sum += __shfl_xor(sum, off); ss += __shfl_xor(ss, off); }
    float mu = sum * (1.f / H);
    float rstd = rsqrtf(ss * (1.f / H) - mu * mu + 1e-5f);
    float xn[16];
    #pragma unroll
    for (int j = 0; j < 16; j++) xn[j] = (v[j] - mu) * rstd * sc[j] + bi[j];
    float acc[NE];
    #pragma unroll
    for (int e = 0; e < NE; e++){
      float g[16];
      loadv16(gw, (size_t)e * H + lane * 16, isf, g);
      float s = 0.f;
      #pragma unroll
      for (int j = 0; j < 16; j++) s += xn[j] * g[j];
      acc[e] = s;
    }
    #pragma unroll
    for (int off = 32; off; off >>= 1){
      #pragma unroll
      for (int e = 0; e < NE; e++) acc[e] += __shfl_xor(acc[e], off);
    }
    if (lane == 0){
      float m = acc[0];
      #pragma unroll
      for (int e = 1; e < NE; e++) m = fmaxf(m, acc[e]);
      float p[NE], Z = 0.f;
      #pragma unroll
      for (int e = 0; e < NE; e++){ p[e] = expf(acc[e] - m); Z += p[e]; }
      float iZ = 1.f / Z;
      #pragma unroll
      for (int e = 0; e < NE; e++) p[e] *= iZ;
      int i1 = 0;
      #pragma unroll
      for (int e = 1; e < NE; e++) if (p[e] > p[i1]) i1 = e;
      int i2 = (i1 == 0) ? 1 : 0;
      #pragma unroll
      for (int e = 0; e < NE; e++) if (e != i1 && p[e] > p[i2]) i2 = e;
      float s2 = p[i1] + p[i2] + 1e-5f;
      int o1 = atomicAdd(&scc[i1], 1);
      int o2 = atomicAdd(&scc[8 + i2], 1);
      sei[0][tl] = i1; soi[0][tl] = o1; swv[0][tl] = p[i1] / s2;
      sei[1][tl] = i2; soi[1][tl] = o2; swv[1][tl] = p[i2] / s2;
    }
  }
  __syncthreads();
  if (tid < 16) sbase[tid] = atomicAdd(&cnt16[tid], scc[tid]);
  __syncthreads();
  if (tid < 2 * BT){
    int l = tid / BT, t = tid % BT;
    int tok = t0 + t;
    if (tok < T){
      int ctr = l * 8 + sei[l][t];
      int pos = sbase[ctr] + soi[l][t];
      lidx[(size_t)ctr * T + pos] = tok;
      lw[(size_t)ctr * T + pos] = swv[l][t];
    }
  }
}

// ---- segment table ----
__global__ __launch_bounds__(64) void scan_k(const int* __restrict__ cnt16,
                                             int* __restrict__ segA, int* __restrict__ segEp,
                                             int* __restrict__ segCnt, int T, int CH,
                                             int L1C, int L2C){
  if (threadIdx.x == 0){
    segA[0] = 0; segEp[0] = T; segCnt[0] = T;
    int b = L1C * CH;
    for (int e = 0; e < 8; e++){
      segA[1 + e] = b; segCnt[1 + e] = cnt16[e];
      b += (cnt16[e] + 255) & ~255;
      segEp[1 + e] = b;
    }
    b = L2C * CH;
    for (int e = 0; e < 8; e++){
      segA[9 + e] = b; segCnt[9 + e] = cnt16[8 + e];
      b += (cnt16[8 + e] + 255) & ~255;
      segEp[9 + e] = b;
    }
  }
}

// ---- 128x128xBK32 GEMM; A via LDS (dbuf, swizzle), B DIRECT global->reg (L2-resident),
// ---- counted vmcnt(6), XCD L2-window remap. Halves LDS-pipe traffic per tile.
// EPI 0: A=x(gathered), B=WguT (N=4096), epilogue silu(g)*u -> hidden (NT stores)
// EPI 2: A=hidden,      B=WdT  (N=1024), epilogue store/RMW -> out
template<int EPI>
__global__ __launch_bounds__(256, 2) void gemm128_k(
    const void* __restrict__ Asrc, const unsigned short* __restrict__ arena,
    unsigned short* __restrict__ hidden, void* __restrict__ outp,
    const int* __restrict__ segA, const int* __restrict__ segEp, const int* __restrict__ segCnt,
    const int* __restrict__ lidx, const float* __restrict__ lw,
    int T, int CH, int c0chunk, const int* __restrict__ flag)
{
  constexpr int K  = (EPI == 2) ? ITR : H;
  constexpr int NT = K / 32;                  // even (32 or 64)

  int tn, tm, chid;
  {
    int P = gridDim.y * gridDim.z;
    int fid = blockIdx.x + gridDim.x * (blockIdx.y + gridDim.y * blockIdx.z);
    if ((P & 7) == 0){
      int xcd = fid & 7;
      int li = fid >> 3;
      int ppx = P >> 3;
      int SS = (EPI == 0) ? 8 : 4;
      if (SS > ppx) SS = ppx;
      int p = li % SS;
      int rest = li / SS;
      tn = rest % (int)gridDim.x;
      int sl = rest / (int)gridDim.x;
      int g = xcd * ppx + sl * SS + p;
      tm = g % (int)gridDim.y;
      chid = c0chunk + g / (int)gridDim.y;
    } else {
      tn = blockIdx.x; tm = blockIdx.y; chid = c0chunk + blockIdx.z;
    }
  }
  int pr0 = chid * CH + tm * 128;

  int s = -1;
  if (pr0 < T) s = 0;
  else {
    #pragma unroll
    for (int i = 1; i <= 16; i++)
      if (pr0 >= segA[i] && pr0 < segEp[i]) s = i;
  }
  if (s < 0) return;
  int cnt = segCnt[s], base = segA[s];
  int slot = (s == 0) ? 8 : ((s - 1) & 7);
  const unsigned short* wT = arena + (size_t)slot * (3u * H * ITR)
                           + (EPI == 2 ? (size_t)2 * H * ITR : 0);
  int isf = *flag;

  __shared__ unsigned short Al[2][128 * 32];   // 16 KB total (A only)

  int tid = threadIdx.x, wid = tid >> 6, l = tid & 63;
  int fr = l & 15, fq = l >> 4;
  int r0l = wid * 32 + (l >> 2);
  int su = (tid & 3) ^ ((l >> 3) & 3);
  int hrow0 = pr0 - c0chunk * CH;
  int wm = (wid >> 1) * 64, wn = (wid & 1) * 64;

  const unsigned short* aptr[2];
  const float* afp[2];
  #pragma unroll
  for (int q = 0; q < 2; q++){
    int rloc = r0l + q * 16;
    if (EPI == 2){
      aptr[q] = (const unsigned short*)Asrc + (size_t)(hrow0 + rloc) * ITR + su * 8;
      afp[q] = nullptr;
    } else {
      int rl = pr0 - base + rloc;
      int rc = cnt - 1; rl = rl < rc ? rl : rc;
      int tok = (s == 0) ? rl : lidx[(size_t)(s - 1) * T + rl];
      aptr[q] = (const unsigned short*)Asrc + (size_t)tok * H + su * 8;
      afp[q]  = (const float*)Asrc + (size_t)tok * H + su * 8;
    }
  }
  // B fragment pointers: direct global, natural (unswizzled) fragment layout
  const unsigned short* bfr[4];
  #pragma unroll
  for (int n = 0; n < 4; n++)
    bfr[n] = wT + (size_t)(tn * 128 + wn + n * 16 + fr) * K + fq * 8;

  f32x4 acc[4][4];
  f32x4 zero4 = {0.f, 0.f, 0.f, 0.f};
  #pragma unroll
  for (int m = 0; m < 4; m++)
    #pragma unroll
    for (int n = 0; n < 4; n++) acc[m][n] = zero4;

  auto stageA = [&](int buf, int kt){
    int k0 = kt * 32;
    #pragma unroll
    for (int q = 0; q < 2; q++){
      int lbyte = (wid * 32 + q * 16) * 64;
      if (EPI == 0 && isf){
        const float* f = afp[q] + k0;
        float4 v0 = *(const float4*)f, v1 = *(const float4*)(f + 4);
        unsigned short w8[8] = {f2bf(v0.x), f2bf(v0.y), f2bf(v0.z), f2bf(v0.w),
                                f2bf(v1.x), f2bf(v1.y), f2bf(v1.z), f2bf(v1.w)};
        *(uint4*)((char*)&Al[buf][0] + (r0l + q * 16) * 64 + (tid & 3) * 16) = *(const uint4*)w8;
      } else {
        gload16(aptr[q] + k0, (char*)&Al[buf][0] + lbyte);
      }
    }
  };

  short8 bA[4], bB[4];
  auto loadB = [&](short8* bd, int kt){
    int k0 = kt * 32;
    #pragma unroll
    for (int n = 0; n < 4; n++)
      bd[n] = *(const short8*)(bfr[n] + k0);
  };

  auto compute = [&](int buf, const short8* b){
    const unsigned short* Ab = &Al[buf][0];
    int un = (fq ^ ((fr >> 1) & 3)) * 8;
    __builtin_amdgcn_s_setprio(1);
    short8 a[4];
    #pragma unroll
    for (int m = 0; m < 4; m++)
      a[m] = *(const short8*)(Ab + (wm + m * 16 + fr) * 32 + un);
    #pragma unroll
    for (int m = 0; m < 4; m++)
      #pragma unroll
      for (int n = 0; n < 4; n++)
        acc[m][n] = __builtin_amdgcn_mfma_f32_16x16x32_bf16(a[m], b[n], acc[m][n], 0, 0, 0);
    __builtin_amdgcn_s_setprio(0);
  };

  // prologue: tile 0 (A -> LDS buf0, B -> regs bA); 6 VMEM ops in flight
  stageA(0, 0); loadB(bA, 0);
  for (int kt = 0; kt < NT; kt += 2){
    // even tile kt: prefetch tile kt+1 (always exists, NT even)
    stageA(1, kt + 1); loadB(bB, kt + 1);
    if (EPI == 0 && isf) asm volatile("s_waitcnt vmcnt(0) lgkmcnt(0)" ::: "memory");
    else                 asm volatile("s_waitcnt vmcnt(6)" ::: "memory");
    __builtin_amdgcn_s_barrier();                 // Al[0] (tile kt) staged for all waves
    compute(0, bA);
    __builtin_amdgcn_s_barrier();                 // all waves done reading Al[0]
    // odd tile kt+1: prefetch tile kt+2 (if any)
    if (kt + 2 < NT){ stageA(0, kt + 2); loadB(bA, kt + 2); }
    if (EPI == 0 && isf)      asm volatile("s_waitcnt vmcnt(0) lgkmcnt(0)" ::: "memory");
    else if (kt + 2 < NT)     asm volatile("s_waitcnt vmcnt(6)" ::: "memory");
    else                      asm volatile("s_waitcnt vmcnt(0)" ::: "memory");
    __builtin_amdgcn_s_barrier();                 // Al[1] (tile kt+1) staged
    compute(1, bB);
    __builtin_amdgcn_s_barrier();                 // all waves done reading Al[1]
  }

  int rb = fq * 4;
  if (EPI == 0){
    int colbase = tn * 64 + (wid & 1) * 32;
    #pragma unroll
    for (int m = 0; m < 4; m++){
      #pragma unroll
      for (int j = 0; j < 4; j++){
        int rl = hrow0 + wm + m * 16 + rb + j;
        unsigned short* hr = hidden + (size_t)rl * ITR + colbase;
        #pragma unroll
        for (int k = 0; k < 2; k++){
          float g = acc[m][k][j], uu = acc[m][k + 2][j];
          __builtin_nontemporal_store(f2bf(g / (1.f + __expf(-g)) * uu), &hr[k * 16 + fr]);
        }
      }
    }
  } else {
    #pragma unroll
    for (int m = 0; m < 4; m++){
      #pragma unroll
      for (int j = 0; j < 4; j++){
        int pr = pr0 + wm + m * 16 + rb + j;
        int rl = pr - base;
        if (rl < cnt){
          int tok = (s == 0) ? rl : lidx[(size_t)(s - 1) * T + rl];
          size_t ob = (size_t)tok * H + tn * 128 + wn + fr;
          if (s == 0){
            if (isf){
              float* p = (float*)outp + ob;
              #pragma unroll
              for (int n = 0; n < 4; n++) __builtin_nontemporal_store(acc[m][n][j], &p[n * 16]);
            } else {
              unsigned short* p = (unsigned short*)outp + ob;
              #pragma unroll
              for (int n = 0; n < 4; n++) __builtin_nontemporal_store(f2bf(acc[m][n][j]), &p[n * 16]);
            }
          } else {
            float wgt = lw[(size_t)(s - 1) * T + rl];
            if (isf){
              float* p = (float*)outp + ob;
              #pragma unroll
              for (int n = 0; n < 4; n++) p[n * 16] += wgt * acc[m][n][j];
            } else {
              unsigned short* p = (unsigned short*)outp + ob;
              #pragma unroll
              for (int n = 0; n < 4; n++) p[n * 16] = f2bf(bf2f(p[n * 16]) + wgt * acc[m][n][j]);
            }
          }
        }
      }
    }
  }
}

extern "C" void kernel_launch(void* const* d_in, const int* in_sizes, int n_in,
                              void* d_out, int out_size, void* d_ws, size_t ws_size,
                              hipStream_t stream)
{
  int T = in_sizes[0] / H;   // 32768

  char* w = (char*)d_ws;
  auto alloc = [&](size_t b){ char* p = w; w += (b + 255) & ~(size_t)255; return p; };
  int* flag   = (int*)alloc(256);
  int* cnt16  = (int*)alloc(256);
  int* segA   = (int*)alloc(256);
  int* segEp  = (int*)alloc(256);
  int* segCnt = (int*)alloc(256);
  int* lidx   = (int*)alloc((size_t)16 * T * 4);
  float* lw   = (float*)alloc((size_t)16 * T * 4);
  const size_t ARENA = (size_t)9 * 3 * H * ITR * 2;
  unsigned short* arena = (unsigned short*)alloc(ARENA);
  size_t used = (size_t)(w - (char*)d_ws);

  int CH = 2048, merged = 0, nh = 1, hidch = 1;
  {
    int mch[3] = {8192, 4096, 2048};
    for (int i = 0; i < 3 && !merged; i++){
      int ch = mch[i];
      int c1 = (T + 8 * 255 + ch - 1) / ch;
      size_t need = used + (size_t)c1 * ch * ITR * 2 + 1024;
      if (need <= ws_size){ merged = 1; CH = ch; hidch = c1; }
    }
    if (!merged){
      struct { int ch, n; } lad[4] = {{8192,2},{8192,1},{4096,1},{2048,1}};
      for (int i = 0; i < 4; i++){
        size_t need = used + (size_t)lad[i].n * lad[i].ch * ITR * 2 + 1024;
        if (need <= ws_size){ CH = lad[i].ch; nh = lad[i].n; hidch = lad[i].n; break; }
      }
    }
  }
  unsigned short* hidden = (unsigned short*)alloc((size_t)hidch * CH * ITR * 2);

  int CB1 = (T + CH - 1) / CH;
  int chunks1 = (T + 8 * 255 + CH - 1) / CH;
  int CB2 = CB1 + chunks1;
  int NCHUNK = CB2 + chunks1;

  detect_k<<<1, 64, 0, stream>>>((const unsigned int*)d_in[0], flag, cnt16);
  router2_k<<<(T + BT - 1) / BT, 256, 0, stream>>>(d_in[0], d_in[1], d_in[2], d_in[3],
                                                   T, flag, cnt16, lidx, lw);
  scan_k<<<1, 64, 0, stream>>>(cnt16, segA, segEp, segCnt, T, CH, CB1, CB2);
  trans_k<<<dim3(32, 32, 27), 256, 0, stream>>>(d_in[4], d_in[5], d_in[6],
                                                d_in[7], d_in[8], d_in[9], arena, flag);

  int bnds[4] = {0, CB1, CB2, NCHUNK};
  if (merged){
    for (int r = 0; r < 3; r++){
      int ng = bnds[r + 1] - bnds[r];
      gemm128_k<0><<<dim3(32, CH / 128, ng), 256, 0, stream>>>(
          d_in[0], arena, hidden, nullptr, segA, segEp, segCnt, lidx, lw,
          T, CH, bnds[r], flag);
      gemm128_k<2><<<dim3(8, CH / 128, ng), 256, 0, stream>>>(
          hidden, arena, hidden, d_out, segA, segEp, segCnt, lidx, lw,
          T, CH, bnds[r], flag);
    }
  } else {
    for (int r = 0; r < 3; r++){
      for (int c = bnds[r]; c < bnds[r + 1]; ){
        int z = (nh == 2 && c + 1 < bnds[r + 1]) ? 2 : 1;
        gemm128_k<0><<<dim3(32, CH / 128, z), 256, 0, stream>>>(
            d_in[0], arena, hidden, nullptr, segA, segEp, segCnt, lidx, lw,
            T, CH, c, flag);
        gemm128_k<2><<<dim3(8, CH / 128, z), 256, 0, stream>>>(
            hidden, arena, hidden, d_out, segA, segEp, segCnt, lidx, lw,
            T, CH, c, flag);
        c += z;
      }
    }
  }
}

// Round 21
// 2445.676 us; speedup vs baseline: 1.5833x; 1.5833x over previous
//
#include <hip/hip_runtime.h>

#define H 1024
#define ITR 2048
#define NE 8
#define BT 32

typedef __attribute__((ext_vector_type(8))) short short8;
typedef __attribute__((ext_vector_type(4))) float f32x4;

__device__ __forceinline__ float bf2f(unsigned short u){
  union { unsigned int i; float f; } v; v.i = ((unsigned int)u) << 16; return v.f;
}
__device__ __forceinline__ unsigned short f2bf(float f){
  union { unsigned int i; float f; } v; v.f = f;
  unsigned int r = v.i + 0x7FFFu + ((v.i >> 16) & 1u);
  return (unsigned short)(r >> 16);
}
__device__ __forceinline__ void gload16(const void* g, void* l){
  __builtin_amdgcn_global_load_lds((const __attribute__((address_space(1))) void*)g,
                                   (__attribute__((address_space(3))) void*)l, 16, 0, 0);
}

// ---- dtype probe ----
__global__ __launch_bounds__(64) void detect_k(const unsigned int* __restrict__ xw,
                                               int* __restrict__ flag, int* __restrict__ cnt16){
  int lane = threadIdx.x;
  int c = 0;
  #pragma unroll
  for (int i = 0; i < 4; i++){
    unsigned u = xw[lane * 4 + i];
    int e = (u >> 7) & 0xFF;
    c += (e >= 100 && e <= 140) ? 1 : 0;
  }
  #pragma unroll
  for (int off = 32; off; off >>= 1) c += __shfl_xor(c, off);
  if (lane == 0) flag[0] = (c < 128) ? 1 : 0;
  if (lane < 16) cnt16[lane] = 0;
}

__device__ __forceinline__ void loadv16(const void* base, size_t off, int isf, float* out){
  if (isf){
    const float* p = (const float*)base + off;
    float4 a = *(const float4*)p, b = *(const float4*)(p + 4);
    float4 c = *(const float4*)(p + 8), d = *(const float4*)(p + 12);
    out[0]=a.x; out[1]=a.y; out[2]=a.z; out[3]=a.w;
    out[4]=b.x; out[5]=b.y; out[6]=b.z; out[7]=b.w;
    out[8]=c.x; out[9]=c.y; out[10]=c.z; out[11]=c.w;
    out[12]=d.x; out[13]=d.y; out[14]=d.z; out[15]=d.w;
  } else {
    const unsigned short* p = (const unsigned short*)base + off;
    uint4 a = *(const uint4*)p, b = *(const uint4*)(p + 8);
    unsigned short u[16];
    *(uint4*)u = a; *(uint4*)(u + 8) = b;
    #pragma unroll
    for (int j = 0; j < 16; j++) out[j] = bf2f(u[j]);
  }
}

// ---- transpose weights; mt 0/1 write INTERLEAVED WguT rows, mt 2 -> WdT ----
// WguT row for channel ch of matrix mt: (ch>>5)*64 + mt*32 + (ch&31)
__global__ __launch_bounds__(256) void trans_k(
    const void* __restrict__ rg, const void* __restrict__ ru, const void* __restrict__ rd,
    const void* __restrict__ sg, const void* __restrict__ su, const void* __restrict__ sd,
    unsigned short* __restrict__ arena, const int* __restrict__ flag)
{
  int slot = blockIdx.z / 3, mt = blockIdx.z % 3;
  int e = slot;                            // slot 8 => shared
  int R = (mt == 2) ? ITR : H;
  int C = (mt == 2) ? H : ITR;
  int c0 = blockIdx.x * 64, r0 = blockIdx.y * 64;
  if (c0 >= C || r0 >= R) return;
  const void* srcv;
  size_t eoff = 0;
  if (e == NE) srcv = (mt == 0) ? sg : ((mt == 1) ? su : sd);
  else { srcv = (mt == 0) ? rg : ((mt == 1) ? ru : rd); eoff = (size_t)e * H * ITR; }
  unsigned short* dst = arena + (size_t)slot * (3u * H * ITR)
                      + (mt == 2 ? (size_t)2 * H * ITR : 0);
  int isf = *flag;
  __shared__ unsigned short tile[64][72];
  int t = threadIdx.x;
  int row = t >> 3, c8 = (t & 7) * 8;
  #pragma unroll
  for (int p = 0; p < 2; p++){
    int r = r0 + row + p * 32;
    unsigned short v[8];
    if (isf){
      const float* s = (const float*)srcv + eoff + (size_t)r * C + c0 + c8;
      float4 a = *(const float4*)s, b = *(const float4*)(s + 4);
      v[0]=f2bf(a.x); v[1]=f2bf(a.y); v[2]=f2bf(a.z); v[3]=f2bf(a.w);
      v[4]=f2bf(b.x); v[5]=f2bf(b.y); v[6]=f2bf(b.z); v[7]=f2bf(b.w);
    } else {
      const unsigned short* s = (const unsigned short*)srcv + eoff + (size_t)r * C + c0 + c8;
      *(uint4*)v = *(const uint4*)s;
    }
    *(uint4*)&tile[row + p * 32][c8] = *(const uint4*)v;
  }
  __syncthreads();
  #pragma unroll
  for (int p = 0; p < 2; p++){
    int c = row + p * 32;
    int dc = c0 + c;
    int dr = (mt == 2) ? dc : (((dc >> 5) << 6) + mt * 32 + (dc & 31));
    unsigned short tmp[8];
    #pragma unroll
    for (int j = 0; j < 8; j++) tmp[j] = tile[c8 + j][c];
    *(uint4*)(dst + (size_t)dr * R + r0 + c8) = *(const uint4*)tmp;
  }
}

// ---- router: two lists (primary ctr 0..7 / secondary 8..15) ----
__global__ __launch_bounds__(256) void router2_k(
    const void* __restrict__ x, const void* __restrict__ lns, const void* __restrict__ lnb,
    const void* __restrict__ gw, int T, const int* __restrict__ flag,
    int* __restrict__ cnt16, int* __restrict__ lidx, float* __restrict__ lw)
{
  int isf = *flag;
  int tid = threadIdx.x, wv = tid >> 6, lane = tid & 63;
  int t0 = blockIdx.x * BT;
  __shared__ int scc[16], sbase[16];
  __shared__ int sei[2][BT], soi[2][BT];
  __shared__ float swv[2][BT];
  if (tid < 16) scc[tid] = 0;
  float sc[16], bi[16];
  loadv16(lns, (size_t)lane * 16, isf, sc);
  loadv16(lnb, (size_t)lane * 16, isf, bi);
  __syncthreads();

  for (int i = 0; i < BT / 4; i++){
    int tl = i * 4 + wv;
    int tok = t0 + tl;
    if (tok >= T) break;
    float v[16];
    loadv16(x, (size_t)tok * H + lane * 16, isf, v);
    float sum = 0.f, ss = 0.f;
    #pragma unroll
    for (int j = 0; j < 16; j++){ sum += v[j]; ss += v[j] * v[j]; }
    #pragma unroll
    for (int off = 32; off; off >>= 1){ sum += __shfl_xor(sum, off); ss += __shfl_xor(ss, off); }
    float mu = sum * (1.f / H);
    float rstd = rsqrtf(ss * (1.f / H) - mu * mu + 1e-5f);
    float xn[16];
    #pragma unroll
    for (int j = 0; j < 16; j++) xn[j] = (v[j] - mu) * rstd * sc[j] + bi[j];
    float acc[NE];
    #pragma unroll
    for (int e = 0; e < NE; e++){
      float g[16];
      loadv16(gw, (size_t)e * H + lane * 16, isf, g);
      float s = 0.f;
      #pragma unroll
      for (int j = 0; j < 16; j++) s += xn[j] * g[j];
      acc[e] = s;
    }
    #pragma unroll
    for (int off = 32; off; off >>= 1){
      #pragma unroll
      for (int e = 0; e < NE; e++) acc[e] += __shfl_xor(acc[e], off);
    }
    if (lane == 0){
      float m = acc[0];
      #pragma unroll
      for (int e = 1; e < NE; e++) m = fmaxf(m, acc[e]);
      float p[NE], Z = 0.f;
      #pragma unroll
      for (int e = 0; e < NE; e++){ p[e] = expf(acc[e] - m); Z += p[e]; }
      float iZ = 1.f / Z;
      #pragma unroll
      for (int e = 0; e < NE; e++) p[e] *= iZ;
      int i1 = 0;
      #pragma unroll
      for (int e = 1; e < NE; e++) if (p[e] > p[i1]) i1 = e;
      int i2 = (i1 == 0) ? 1 : 0;
      #pragma unroll
      for (int e = 0; e < NE; e++) if (e != i1 && p[e] > p[i2]) i2 = e;
      float s2 = p[i1] + p[i2] + 1e-5f;
      int o1 = atomicAdd(&scc[i1], 1);
      int o2 = atomicAdd(&scc[8 + i2], 1);
      sei[0][tl] = i1; soi[0][tl] = o1; swv[0][tl] = p[i1] / s2;
      sei[1][tl] = i2; soi[1][tl] = o2; swv[1][tl] = p[i2] / s2;
    }
  }
  __syncthreads();
  if (tid < 16) sbase[tid] = atomicAdd(&cnt16[tid], scc[tid]);
  __syncthreads();
  if (tid < 2 * BT){
    int l = tid / BT, t = tid % BT;
    int tok = t0 + t;
    if (tok < T){
      int ctr = l * 8 + sei[l][t];
      int pos = sbase[ctr] + soi[l][t];
      lidx[(size_t)ctr * T + pos] = tok;
      lw[(size_t)ctr * T + pos] = swv[l][t];
    }
  }
}

// ---- segment table ----
__global__ __launch_bounds__(64) void scan_k(const int* __restrict__ cnt16,
                                             int* __restrict__ segA, int* __restrict__ segEp,
                                             int* __restrict__ segCnt, int T, int CH,
                                             int L1C, int L2C){
  if (threadIdx.x == 0){
    segA[0] = 0; segEp[0] = T; segCnt[0] = T;
    int b = L1C * CH;
    for (int e = 0; e < 8; e++){
      segA[1 + e] = b; segCnt[1 + e] = cnt16[e];
      b += (cnt16[e] + 255) & ~255;
      segEp[1 + e] = b;
    }
    b = L2C * CH;
    for (int e = 0; e < 8; e++){
      segA[9 + e] = b; segCnt[9 + e] = cnt16[8 + e];
      b += (cnt16[8 + e] + 255) & ~255;
      segEp[9 + e] = b;
    }
  }
}

// ---- 128x128xBK32 GEMM, dbuf + counted vmcnt, swizzled LDS, XCD L2-window remap ----
// EPI 0: A=x(gathered), B=WguT (N=4096), epilogue silu(g)*u -> hidden (NT stores)
// EPI 2: A=hidden,      B=WdT  (N=1024), epilogue store/RMW -> out
template<int EPI>
__global__ __launch_bounds__(256, 2) void gemm128_k(
    const void* __restrict__ Asrc, const unsigned short* __restrict__ arena,
    unsigned short* __restrict__ hidden, void* __restrict__ outp,
    const int* __restrict__ segA, const int* __restrict__ segEp, const int* __restrict__ segCnt,
    const int* __restrict__ lidx, const float* __restrict__ lw,
    int T, int CH, int c0chunk, const int* __restrict__ flag)
{
  constexpr int K  = (EPI == 2) ? ITR : H;
  constexpr int NT = K / 32;

  int tn, tm, chid;
  {
    int P = gridDim.y * gridDim.z;
    int fid = blockIdx.x + gridDim.x * (blockIdx.y + gridDim.y * blockIdx.z);
    if ((P & 7) == 0){
      int xcd = fid & 7;
      int li = fid >> 3;
      int ppx = P >> 3;
      int SS = (EPI == 0) ? 8 : 4;
      if (SS > ppx) SS = ppx;
      int p = li % SS;
      int rest = li / SS;
      tn = rest % (int)gridDim.x;
      int sl = rest / (int)gridDim.x;
      int g = xcd * ppx + sl * SS + p;
      tm = g % (int)gridDim.y;
      chid = c0chunk + g / (int)gridDim.y;
    } else {
      tn = blockIdx.x; tm = blockIdx.y; chid = c0chunk + blockIdx.z;
    }
  }
  int pr0 = chid * CH + tm * 128;

  int s = -1;
  if (pr0 < T) s = 0;
  else {
    #pragma unroll
    for (int i = 1; i <= 16; i++)
      if (pr0 >= segA[i] && pr0 < segEp[i]) s = i;
  }
  if (s < 0) return;
  int cnt = segCnt[s], base = segA[s];
  int slot = (s == 0) ? 8 : ((s - 1) & 7);
  const unsigned short* wT = arena + (size_t)slot * (3u * H * ITR)
                           + (EPI == 2 ? (size_t)2 * H * ITR : 0);
  int isf = *flag;

  __shared__ unsigned short Al[2][128 * 32];
  __shared__ unsigned short Bl[2][128 * 32];

  int tid = threadIdx.x, wid = tid >> 6, l = tid & 63;
  int fr = l & 15, fq = l >> 4;
  int r0l = wid * 32 + (l >> 2);
  int su = (tid & 3) ^ ((l >> 3) & 3);
  int hrow0 = pr0 - c0chunk * CH;

  const unsigned short* aptr[2];
  const float* afp[2];
  #pragma unroll
  for (int q = 0; q < 2; q++){
    int rloc = r0l + q * 16;
    if (EPI == 2){
      aptr[q] = (const unsigned short*)Asrc + (size_t)(hrow0 + rloc) * ITR + su * 8;
      afp[q] = nullptr;
    } else {
      int rl = pr0 - base + rloc;
      int rc = cnt - 1; rl = rl < rc ? rl : rc;
      int tok = (s == 0) ? rl : lidx[(size_t)(s - 1) * T + rl];
      aptr[q] = (const unsigned short*)Asrc + (size_t)tok * H + su * 8;
      afp[q]  = (const float*)Asrc + (size_t)tok * H + su * 8;
    }
  }
  const unsigned short* bptr[2];
  #pragma unroll
  for (int q = 0; q < 2; q++)
    bptr[q] = wT + (size_t)(tn * 128 + r0l + q * 16) * K + su * 8;

  f32x4 acc[4][4];
  f32x4 zero4 = {0.f, 0.f, 0.f, 0.f};
  #pragma unroll
  for (int m = 0; m < 4; m++)
    #pragma unroll
    for (int n = 0; n < 4; n++) acc[m][n] = zero4;

  int wm = (wid >> 1) * 64, wn = (wid & 1) * 64;

  auto stage = [&](int buf, int kt){
    int k0 = kt * 32;
    #pragma unroll
    for (int q = 0; q < 2; q++){
      int lbyte = (wid * 32 + q * 16) * 64;
      if (EPI == 0 && isf){
        const float* f = afp[q] + k0;
        float4 v0 = *(const float4*)f, v1 = *(const float4*)(f + 4);
        unsigned short w8[8] = {f2bf(v0.x), f2bf(v0.y), f2bf(v0.z), f2bf(v0.w),
                                f2bf(v1.x), f2bf(v1.y), f2bf(v1.z), f2bf(v1.w)};
        *(uint4*)((char*)&Al[buf][0] + (r0l + q * 16) * 64 + (tid & 3) * 16) = *(const uint4*)w8;
      } else {
        gload16(aptr[q] + k0, (char*)&Al[buf][0] + lbyte);
      }
      gload16(bptr[q] + k0, (char*)&Bl[buf][0] + lbyte);
    }
  };

  auto compute = [&](int buf){
    const unsigned short* Ab = &Al[buf][0];
    const unsigned short* Bb = &Bl[buf][0];
    int un = (fq ^ ((fr >> 1) & 3)) * 8;
    __builtin_amdgcn_s_setprio(1);
    short8 a[4], b[4];
    #pragma unroll
    for (int m = 0; m < 4; m++)
      a[m] = *(const short8*)(Ab + (wm + m * 16 + fr) * 32 + un);
    #pragma unroll
    for (int n = 0; n < 4; n++)
      b[n] = *(const short8*)(Bb + (wn + n * 16 + fr) * 32 + un);
    #pragma unroll
    for (int m = 0; m < 4; m++)
      #pragma unroll
      for (int n = 0; n < 4; n++)
        acc[m][n] = __builtin_amdgcn_mfma_f32_16x16x32_bf16(a[m], b[n], acc[m][n], 0, 0, 0);
    __builtin_amdgcn_s_setprio(0);
  };

  stage(0, 0);
  int cur = 0;
  for (int kt = 0; kt < NT; kt++){
    if (kt + 1 < NT) stage(cur ^ 1, kt + 1);
    if (EPI == 0 && isf) asm volatile("s_waitcnt lgkmcnt(0)" ::: "memory");
    if (kt + 1 < NT){
      if (EPI == 0 && isf) asm volatile("s_waitcnt vmcnt(2)" ::: "memory");
      else                 asm volatile("s_waitcnt vmcnt(4)" ::: "memory");
    } else {
      asm volatile("s_waitcnt vmcnt(0)" ::: "memory");
    }
    __builtin_amdgcn_s_barrier();
    compute(cur);
    __builtin_amdgcn_s_barrier();
    cur ^= 1;
  }

  int rb = fq * 4;
  if (EPI == 0){
    int colbase = tn * 64 + (wid & 1) * 32;
    #pragma unroll
    for (int m = 0; m < 4; m++){
      #pragma unroll
      for (int j = 0; j < 4; j++){
        int rl = hrow0 + wm + m * 16 + rb + j;
        unsigned short* hr = hidden + (size_t)rl * ITR + colbase;
        #pragma unroll
        for (int k = 0; k < 2; k++){
          float g = acc[m][k][j], uu = acc[m][k + 2][j];
          __builtin_nontemporal_store(f2bf(g / (1.f + __expf(-g)) * uu), &hr[k * 16 + fr]);
        }
      }
    }
  } else {
    #pragma unroll
    for (int m = 0; m < 4; m++){
      #pragma unroll
      for (int j = 0; j < 4; j++){
        int pr = pr0 + wm + m * 16 + rb + j;
        int rl = pr - base;
        if (rl < cnt){
          int tok = (s == 0) ? rl : lidx[(size_t)(s - 1) * T + rl];
          size_t ob = (size_t)tok * H + tn * 128 + wn + fr;
          if (s == 0){
            if (isf){
              float* p = (float*)outp + ob;
              #pragma unroll
              for (int n = 0; n < 4; n++) __builtin_nontemporal_store(acc[m][n][j], &p[n * 16]);
            } else {
              unsigned short* p = (unsigned short*)outp + ob;
              #pragma unroll
              for (int n = 0; n < 4; n++) __builtin_nontemporal_store(f2bf(acc[m][n][j]), &p[n * 16]);
            }
          } else {
            float wgt = lw[(size_t)(s - 1) * T + rl];
            if (isf){
              float* p = (float*)outp + ob;
              #pragma unroll
              for (int n = 0; n < 4; n++) p[n * 16] += wgt * acc[m][n][j];
            } else {
              unsigned short* p = (unsigned short*)outp + ob;
              #pragma unroll
              for (int n = 0; n < 4; n++) p[n * 16] = f2bf(bf2f(p[n * 16]) + wgt * acc[m][n][j]);
            }
          }
        }
      }
    }
  }
}

extern "C" void kernel_launch(void* const* d_in, const int* in_sizes, int n_in,
                              void* d_out, int out_size, void* d_ws, size_t ws_size,
                              hipStream_t stream)
{
  int T = in_sizes[0] / H;   // 32768

  char* w = (char*)d_ws;
  auto alloc = [&](size_t b){ char* p = w; w += (b + 255) & ~(size_t)255; return p; };
  int* flag   = (int*)alloc(256);
  int* cnt16  = (int*)alloc(256);
  int* segA   = (int*)alloc(256);
  int* segEp  = (int*)alloc(256);
  int* segCnt = (int*)alloc(256);
  int* lidx   = (int*)alloc((size_t)16 * T * 4);
  float* lw   = (float*)alloc((size_t)16 * T * 4);
  const size_t ARENA = (size_t)9 * 3 * H * ITR * 2;
  unsigned short* arena = (unsigned short*)alloc(ARENA);
  size_t used = (size_t)(w - (char*)d_ws);

  int CH = 2048, merged = 0, nh = 1, hidch = 1;
  {
    int mch[3] = {8192, 4096, 2048};
    for (int i = 0; i < 3 && !merged; i++){
      int ch = mch[i];
      int c1 = (T + 8 * 255 + ch - 1) / ch;
      size_t need = used + (size_t)c1 * ch * ITR * 2 + 1024;
      if (need <= ws_size){ merged = 1; CH = ch; hidch = c1; }
    }
    if (!merged){
      struct { int ch, n; } lad[4] = {{8192,2},{8192,1},{4096,1},{2048,1}};
      for (int i = 0; i < 4; i++){
        size_t need = used + (size_t)lad[i].n * lad[i].ch * ITR * 2 + 1024;
        if (need <= ws_size){ CH = lad[i].ch; nh = lad[i].n; hidch = lad[i].n; break; }
      }
    }
  }
  unsigned short* hidden = (unsigned short*)alloc((size_t)hidch * CH * ITR * 2);

  int CB1 = (T + CH - 1) / CH;
  int chunks1 = (T + 8 * 255 + CH - 1) / CH;
  int CB2 = CB1 + chunks1;
  int NCHUNK = CB2 + chunks1;

  detect_k<<<1, 64, 0, stream>>>((const unsigned int*)d_in[0], flag, cnt16);
  router2_k<<<(T + BT - 1) / BT, 256, 0, stream>>>(d_in[0], d_in[1], d_in[2], d_in[3],
                                                   T, flag, cnt16, lidx, lw);
  scan_k<<<1, 64, 0, stream>>>(cnt16, segA, segEp, segCnt, T, CH, CB1, CB2);
  trans_k<<<dim3(32, 32, 27), 256, 0, stream>>>(d_in[4], d_in[5], d_in[6],
                                                d_in[7], d_in[8], d_in[9], arena, flag);

  int bnds[4] = {0, CB1, CB2, NCHUNK};
  if (merged){
    for (int r = 0; r < 3; r++){
      int ng = bnds[r + 1] - bnds[r];
      gemm128_k<0><<<dim3(32, CH / 128, ng), 256, 0, stream>>>(
          d_in[0], arena, hidden, nullptr, segA, segEp, segCnt, lidx, lw,
          T, CH, bnds[r], flag);
      gemm128_k<2><<<dim3(8, CH / 128, ng), 256, 0, stream>>>(
          hidden, arena, hidden, d_out, segA, segEp, segCnt, lidx, lw,
          T, CH, bnds[r], flag);
    }
  } else {
    for (int r = 0; r < 3; r++){
      for (int c = bnds[r]; c < bnds[r + 1]; ){
        int z = (nh == 2 && c + 1 < bnds[r + 1]) ? 2 : 1;
        gemm128_k<0><<<dim3(32, CH / 128, z), 256, 0, stream>>>(
            d_in[0], arena, hidden, nullptr, segA, segEp, segCnt, lidx, lw,
            T, CH, c, flag);
        gemm128_k<2><<<dim3(8, CH / 128, z), 256, 0, stream>>>(
            hidden, arena, hidden, d_out, segA, segEp, segCnt, lidx, lw,
            T, CH, c, flag);
        c += z;
      }
    }
  }
}